// Round 3
// baseline (155.676 us; speedup 1.0000x reference)
//
#include <hip/hip_runtime.h>
#include <hip/hip_bf16.h>
#include <stdint.h>

// Problem constants
#define MB 8192     // batch (rows and cols of sim)
#define KD 256      // embedding dim
#define BM 128      // rows per block (4 waves x 32 rows)
#define BN 64       // cols per chunk
#define NSPLIT 16   // column slabs (1024 blocks = 4 blocks/CU on 256 CUs)
#define SLAB (MB / NSPLIT)   // 512 cols per slab
#define VOCAB 1000000
#define COFF 104.0f          // fixed exp offset (overflow/underflow-safe)
#define LOG2E 1.44269504088896340736f

typedef __attribute__((ext_vector_type(8))) short bf16x8;
typedef __attribute__((ext_vector_type(4))) float f32x4;

__device__ __forceinline__ unsigned short f2bf(float x) {
  union { float f; uint32_t u; } v; v.f = x;
  uint32_t r = v.u + 0x7fffu + ((v.u >> 16) & 1u);   // RNE
  return (unsigned short)(r >> 16);
}

__device__ __forceinline__ float fast_exp2(float x) {
#if __has_builtin(__builtin_amdgcn_exp2f)
  return __builtin_amdgcn_exp2f(x);
#else
  return exp2f(x);
#endif
}

// async global->LDS DMA, 16B per lane, LDS dest = wave-uniform base + lane*16
#define GLOAD_LDS16(g, l)                                                      \
  __builtin_amdgcn_global_load_lds(                                            \
      (const __attribute__((address_space(1))) void*)(g),                      \
      (__attribute__((address_space(3))) void*)(l), 16, 0, 0)

// ---- convert fp32->bf16 for A,B + pos_sim (fp32, wave per row) + zero hist ----
__global__ __launch_bounds__(256) void convertpos_kernel(
    const float* __restrict__ A, const float* __restrict__ B,
    unsigned short* __restrict__ Abf, unsigned short* __restrict__ Bbf,
    float* __restrict__ pos, int* __restrict__ hist) {
  int t = blockIdx.x * 256 + threadIdx.x;        // 524288 threads, 1 float4 each
  const float4 a = ((const float4*)A)[t];
  const float4 b = ((const float4*)B)[t];
  ushort4 oa, ob;
  oa.x = f2bf(a.x); oa.y = f2bf(a.y); oa.z = f2bf(a.z); oa.w = f2bf(a.w);
  ob.x = f2bf(b.x); ob.y = f2bf(b.y); ob.z = f2bf(b.z); ob.w = f2bf(b.w);
  ((ushort4*)Abf)[t] = oa;
  ((ushort4*)Bbf)[t] = ob;
  // pos_sim: wave (t>>6) == row, 64 lanes cover KD/4 float4 chunks
  float d = a.x * b.x + a.y * b.y + a.z * b.z + a.w * b.w;
  #pragma unroll
  for (int off = 32; off; off >>= 1) d += __shfl_down(d, off, 64);
  if ((threadIdx.x & 63) == 0) pos[t >> 6] = d;
  // zero the vocab histogram (1M ints == 524288 uint2)
  ((uint2*)hist)[t] = make_uint2(0u, 0u);
}

// ---- histogram of ids + b2 = -(log2 q + C*log2e) + zero accumulators ----
__global__ __launch_bounds__(256) void histb2_kernel(
    const int* __restrict__ ids, const float* __restrict__ q,
    int* __restrict__ hist, float* __restrict__ b2,
    float* __restrict__ ps, float* __restrict__ out) {
  int i = blockIdx.x * 256 + threadIdx.x;   // 32 blocks -> 8192 threads
  atomicAdd(&hist[ids[i]], 1);
  // exp(sim - ln q - C) == exp2(sim*LOG2E + b2), b2 = -(log2 q + C*LOG2E)
  b2[i] = -(log2f(q[i]) + COFF * LOG2E);
  ps[i] = 0.0f;
  if (i == 0) out[0] = 0.0f;
}

// ---- fused GEMM + masked fixed-offset exp-sum ----
__global__ __launch_bounds__(256, 4) void fused_kernel(
    const unsigned short* __restrict__ Abf,
    const unsigned short* __restrict__ Bbf,
    const int* __restrict__ ids,
    const float* __restrict__ b2,
    float* __restrict__ ps) {
  const int slab = blockIdx.y;
  const int tid = threadIdx.x;
  const int wave = tid >> 6;
  const int lane = tid & 63;
  const int quad = lane >> 4;
  const int lpos = lane & 15;
  const int rowbase = blockIdx.x * BM + wave * 32;

  // Fragment-ordered B staging: cell c = ((ct*8+kb)*4+quad)*16+lpos holds
  // B[col = ct*16+lpos][k = kb*32+quad*8 .. +8). Frag reads are wave-linear
  // (lane i -> byte 16*i) => conflict-free ds_read_b128. Layout is linear in
  // c == tid + s8*256, so global_load_lds's uniform-base+lane*16 dest matches.
  __shared__ unsigned short Bs[2048 * 8];    // 32 KB

  // A fragments resident: wave owns rows [rowbase, rowbase+32)
  bf16x8 afrag[2][8];
  #pragma unroll
  for (int rt = 0; rt < 2; ++rt)
    #pragma unroll
    for (int kb = 0; kb < 8; ++kb)
      afrag[rt][kb] = *(const bf16x8*)(Abf + (rowbase + rt * 16 + lpos) * KD + kb * 32 + quad * 8);

  // chunk-invariant staging addresses (advance global side by ch*BN*KD)
  const unsigned short* gsrc[8];
  unsigned short* ldst[8];
  #pragma unroll
  for (int s8 = 0; s8 < 8; ++s8) {
    int c = tid + s8 * 256;
    int lp = c & 15, qd = (c >> 4) & 3, kb = (c >> 6) & 7, ct = c >> 9;
    gsrc[s8] = Bbf + (slab * SLAB + ct * 16 + lp) * KD + kb * 32 + qd * 8;
    ldst[s8] = Bs + c * 8;
  }

  int idr[2][4];
  float srun[2][4];
  #pragma unroll
  for (int rt = 0; rt < 2; ++rt)
    #pragma unroll
    for (int r = 0; r < 4; ++r) {
      idr[rt][r] = ids[rowbase + rt * 16 + quad * 4 + r];
      srun[rt][r] = 0.0f;
    }

  for (int ch = 0; ch < SLAB / BN; ++ch) {
    const int colchunk = slab * SLAB + ch * BN;
    __syncthreads();                         // protect Bs from overwrite
    #pragma unroll
    for (int s8 = 0; s8 < 8; ++s8)
      GLOAD_LDS16(gsrc[s8] + ch * (BN * KD), ldst[s8]);
    __syncthreads();                         // drains vmcnt(0): Bs ready

    #pragma unroll
    for (int ct = 0; ct < 4; ++ct) {
      const unsigned short* bp = Bs + (ct * 512 + quad * 16 + lpos) * 8;
      bf16x8 bfrag[8];
      #pragma unroll
      for (int kb = 0; kb < 8; ++kb)
        bfrag[kb] = *(const bf16x8*)(bp + kb * 512);
      const int j = colchunk + ct * 16 + lpos;
      const int idj = ids[j];
      const float bj = b2[j];
      #pragma unroll
      for (int rt = 0; rt < 2; ++rt) {
        f32x4 acc = {0.0f, 0.0f, 0.0f, 0.0f};
        #pragma unroll
        for (int kb = 0; kb < 8; ++kb)
          acc = __builtin_amdgcn_mfma_f32_16x16x32_bf16(afrag[rt][kb], bfrag[kb], acc, 0, 0, 0);
        // lane holds sim[rt*16 + quad*4 + r][ct*16 + lpos]
        #pragma unroll
        for (int r = 0; r < 4; ++r) {
          const float e = fast_exp2(__builtin_fmaf(acc[r], LOG2E, bj));
          srun[rt][r] += (idj != idr[rt][r]) ? e : 0.0f;
        }
      }
    }
  }

  // sum across the 16 lanes of each quad (the 16 columns of the frag)
  #pragma unroll
  for (int rt = 0; rt < 2; ++rt)
    #pragma unroll
    for (int r = 0; r < 4; ++r) {
      float v = srun[rt][r];
      #pragma unroll
      for (int off = 1; off < 16; off <<= 1) v += __shfl_xor(v, off, 64);
      if (lpos == 0)
        atomicAdd(&ps[rowbase + rt * 16 + quad * 4 + r], v);
    }
}

// ---- finalize: per-row loss, mean ----
__global__ __launch_bounds__(256) void finalize_kernel(
    const float* __restrict__ ps, const float* __restrict__ pos,
    const float* __restrict__ q, const int* __restrict__ ids,
    const int* __restrict__ hist, float* __restrict__ out) {
  int i = blockIdx.x * 256 + threadIdx.x;   // 32 blocks -> 8192 threads
  const float s = ps[i];
  const float nm = (float)(MB - hist[ids[i]]);
  // log S_i = log(s) + C + log(1-q_i) - log(n_miss)
  const float z = logf(s) + COFF + logf(1.0f - q[i]) - logf(nm);
  const float p = pos[i];
  const float hi = fmaxf(p, z), lo = fminf(p, z);
  float loss = -p + hi + log1pf(__expf(lo - hi));

  #pragma unroll
  for (int off = 32; off; off >>= 1) loss += __shfl_down(loss, off, 64);
  __shared__ float red[4];
  if ((threadIdx.x & 63) == 0) red[threadIdx.x >> 6] = loss;
  __syncthreads();
  if (threadIdx.x == 0) {
    float t = red[0] + red[1] + red[2] + red[3];
    atomicAdd(out, t * (1.0f / (float)MB));
  }
}

extern "C" void kernel_launch(void* const* d_in, const int* in_sizes, int n_in,
                              void* d_out, int out_size, void* d_ws, size_t ws_size,
                              hipStream_t stream) {
  (void)in_sizes; (void)n_in; (void)out_size; (void)ws_size;
  const float* input_emb  = (const float*)d_in[0];
  const float* target_emb = (const float*)d_in[1];
  const int*   target_ids = (const int*)d_in[2];
  const float* q_probas   = (const float*)d_in[3];
  float* out = (float*)d_out;

  char* ws = (char*)d_ws;
  unsigned short* Abf = (unsigned short*)(ws);                    // 4 MB
  unsigned short* Bbf = (unsigned short*)(ws + (4u << 20));       // 4 MB
  int*   hist = (int*)  (ws + (8u << 20));                        // 4 MB
  float* b2   = (float*)(ws + (12u << 20));                       // 32 KB
  float* pos  = (float*)(ws + (12u << 20) + 32768);               // 32 KB
  float* ps   = (float*)(ws + (12u << 20) + 65536);               // 32 KB

  convertpos_kernel<<<2048, 256, 0, stream>>>(input_emb, target_emb, Abf, Bbf, pos, hist);
  histb2_kernel<<<32, 256, 0, stream>>>(target_ids, q_probas, hist, b2, ps, out);
  fused_kernel<<<dim3(MB / BM, NSPLIT), 256, 0, stream>>>(Abf, Bbf, target_ids, b2, ps);
  finalize_kernel<<<32, 256, 0, stream>>>(ps, pos, q_probas, target_ids, hist, out);
}

// Round 6
// 119.475 us; speedup vs baseline: 1.3030x; 1.3030x over previous
//
#include <hip/hip_runtime.h>
#include <hip/hip_bf16.h>
#include <stdint.h>

// Problem constants
#define MB 8192     // batch (rows and cols of sim)
#define KD 256      // embedding dim
#define BM 128      // rows per block (4 waves x 32 rows)
#define BN 64       // cols per chunk
#define NSPLIT 8    // column slabs (512 blocks: proven-good L2 behavior, 18.7MB fetch)
#define SLAB (MB / NSPLIT)   // 1024 cols per slab
#define NCHUNK (SLAB / BN)   // 16 chunks per slab
#define VOCAB 1000000
#define COFF 104.0f          // fixed exp offset (overflow/underflow-safe)
#define LOG2E 1.44269504088896340736f

typedef __attribute__((ext_vector_type(8))) short bf16x8;
typedef __attribute__((ext_vector_type(4))) float f32x4;

__device__ __forceinline__ unsigned short f2bf(float x) {
  union { float f; uint32_t u; } v; v.f = x;
  uint32_t r = v.u + 0x7fffu + ((v.u >> 16) & 1u);   // RNE
  return (unsigned short)(r >> 16);
}

__device__ __forceinline__ float fast_exp2(float x) {
#if __has_builtin(__builtin_amdgcn_exp2f)
  return __builtin_amdgcn_exp2f(x);
#else
  return exp2f(x);
#endif
}

// async global->LDS DMA, 16B per lane, LDS dest = wave-uniform base + lane*16
#define GLOAD_LDS16(g, l)                                                      \
  __builtin_amdgcn_global_load_lds(                                            \
      (const __attribute__((address_space(1))) void*)(g),                      \
      (__attribute__((address_space(3))) void*)(l), 16, 0, 0)

// ---- convert fp32->bf16 for A,B + pos_sim (fp32, wave per row) + zero hist ----
__global__ __launch_bounds__(256) void convertpos_kernel(
    const float* __restrict__ A, const float* __restrict__ B,
    unsigned short* __restrict__ Abf, unsigned short* __restrict__ Bbf,
    float* __restrict__ pos, int* __restrict__ hist) {
  int t = blockIdx.x * 256 + threadIdx.x;        // 524288 threads, 1 float4 each
  const float4 a = ((const float4*)A)[t];
  const float4 b = ((const float4*)B)[t];
  ushort4 oa, ob;
  oa.x = f2bf(a.x); oa.y = f2bf(a.y); oa.z = f2bf(a.z); oa.w = f2bf(a.w);
  ob.x = f2bf(b.x); ob.y = f2bf(b.y); ob.z = f2bf(b.z); ob.w = f2bf(b.w);
  ((ushort4*)Abf)[t] = oa;
  ((ushort4*)Bbf)[t] = ob;
  // pos_sim: wave (t>>6) == row, 64 lanes cover KD/4 float4 chunks
  float d = a.x * b.x + a.y * b.y + a.z * b.z + a.w * b.w;
  #pragma unroll
  for (int off = 32; off; off >>= 1) d += __shfl_down(d, off, 64);
  if ((threadIdx.x & 63) == 0) pos[t >> 6] = d;
  // zero the vocab histogram (1M ints == 524288 uint2)
  ((uint2*)hist)[t] = make_uint2(0u, 0u);
}

// ---- histogram of ids + b2 = -(log2 q + C*log2e) + zero accumulators ----
__global__ __launch_bounds__(256) void histb2_kernel(
    const int* __restrict__ ids, const float* __restrict__ q,
    int* __restrict__ hist, float* __restrict__ b2,
    float* __restrict__ ps, float* __restrict__ out) {
  int i = blockIdx.x * 256 + threadIdx.x;   // 32 blocks -> 8192 threads
  atomicAdd(&hist[ids[i]], 1);
  // exp(sim - ln q - C) == exp2(sim*LOG2E + b2), b2 = -(log2 q + C*LOG2E)
  b2[i] = -(log2f(q[i]) + COFF * LOG2E);
  ps[i] = 0.0f;
  if (i == 0) out[0] = 0.0f;
}

// ---- fused GEMM + masked fixed-offset exp-sum, 2-phase double-buffered ----
__global__ __launch_bounds__(256, 2) void fused_kernel(
    const unsigned short* __restrict__ Abf,
    const unsigned short* __restrict__ Bbf,
    const int* __restrict__ ids,
    const float* __restrict__ b2,
    float* __restrict__ ps) {
  const int slab = blockIdx.y;
  const int tid = threadIdx.x;
  const int wave = tid >> 6;
  const int lane = tid & 63;
  const int quad = lane >> 4;
  const int lpos = lane & 15;
  const int rowbase = blockIdx.x * BM + wave * 32;
  const int colbase = slab * SLAB;

  // Fragment-ordered B staging, DOUBLE buffered: cell c = ((ct*8+kb)*4+quad)*16+lpos
  // holds B[col = ct*16+lpos][k = kb*32+quad*8 .. +8). Linear in c == tid + s8*256,
  // matching global_load_lds's uniform-base+lane*16 dest. Frag reads wave-linear
  // (lane i -> byte 16*i) => conflict-free ds_read_b128.
  __shared__ unsigned short Bs[2][2048 * 8];   // 2 x 32 KB (2 blocks/CU -> 128 KB)

  // A fragments resident: wave owns rows [rowbase, rowbase+32)
  bf16x8 afrag[2][8];
  #pragma unroll
  for (int rt = 0; rt < 2; ++rt)
    #pragma unroll
    for (int kb = 0; kb < 8; ++kb)
      afrag[rt][kb] = *(const bf16x8*)(Abf + (rowbase + rt * 16 + lpos) * KD + kb * 32 + quad * 8);

  // chunk-invariant staging addresses (advance global side by chunk*BN*KD)
  const unsigned short* gsrc[8];
  int ldso[8];                               // short-offset within one buffer
  #pragma unroll
  for (int s8 = 0; s8 < 8; ++s8) {
    int c = tid + s8 * 256;
    int lp = c & 15, qd = (c >> 4) & 3, kb = (c >> 6) & 7, ct = c >> 9;
    gsrc[s8] = Bbf + (colbase + ct * 16 + lp) * KD + kb * 32 + qd * 8;
    ldso[s8] = c * 8;
  }

  int idr[2][4];
  float srun[2][4];
  #pragma unroll
  for (int rt = 0; rt < 2; ++rt)
    #pragma unroll
    for (int r = 0; r < 4; ++r) {
      idr[rt][r] = ids[rowbase + rt * 16 + quad * 4 + r];
      srun[rt][r] = 0.0f;
    }

  // Prologue: prefetch ids/b2 + B-tile for chunk 0
  int idv[2][4];
  float bv[2][4];
  #pragma unroll
  for (int ct = 0; ct < 4; ++ct) {
    idv[0][ct] = ids[colbase + ct * 16 + lpos];
    bv[0][ct]  = b2 [colbase + ct * 16 + lpos];
  }
  #pragma unroll
  for (int s8 = 0; s8 < 8; ++s8)
    GLOAD_LDS16(gsrc[s8], &Bs[0][0] + ldso[s8]);
  __syncthreads();                           // drains vmcnt(0): chunk 0 ready

  // Per iteration: issue next-chunk ids/b2 loads FIRST (so their vmcnt retires
  // before the DMAs'), then next-chunk DMA, then compute current chunk from
  // registers+LDS only (no vmem wait inside compute). __syncthreads() at the
  // end drains the prefetch -- its latency hid under ~1100 cy of MFMA+exp.
#define FUSED_BODY(T, CUR)                                                     \
  {                                                                            \
    const int nxt = (T) + 1;                                                   \
    if (nxt < NCHUNK) {                                                        \
      _Pragma("unroll")                                                        \
      for (int ct = 0; ct < 4; ++ct) {                                         \
        idv[(CUR) ^ 1][ct] = ids[colbase + nxt * BN + ct * 16 + lpos];         \
        bv[(CUR) ^ 1][ct]  = b2 [colbase + nxt * BN + ct * 16 + lpos];         \
      }                                                                        \
      _Pragma("unroll")                                                        \
      for (int s8 = 0; s8 < 8; ++s8)                                           \
        GLOAD_LDS16(gsrc[s8] + nxt * (BN * KD), &Bs[(CUR) ^ 1][0] + ldso[s8]); \
    }                                                                          \
    _Pragma("unroll")                                                          \
    for (int ct = 0; ct < 4; ++ct) {                                           \
      const unsigned short* bp = &Bs[CUR][0] + (ct * 512 + quad * 16 + lpos) * 8; \
      bf16x8 bfrag[8];                                                         \
      _Pragma("unroll")                                                        \
      for (int kb = 0; kb < 8; ++kb)                                           \
        bfrag[kb] = *(const bf16x8*)(bp + kb * 512);                           \
      const int idj = idv[CUR][ct];                                            \
      const float bj = bv[CUR][ct];                                            \
      _Pragma("unroll")                                                        \
      for (int rt = 0; rt < 2; ++rt) {                                         \
        f32x4 acc = {0.0f, 0.0f, 0.0f, 0.0f};                                  \
        _Pragma("unroll")                                                      \
        for (int kb = 0; kb < 8; ++kb)                                         \
          acc = __builtin_amdgcn_mfma_f32_16x16x32_bf16(afrag[rt][kb], bfrag[kb], acc, 0, 0, 0); \
        _Pragma("unroll")                                                      \
        for (int r = 0; r < 4; ++r) {                                          \
          const float e = fast_exp2(__builtin_fmaf(acc[r], LOG2E, bj));        \
          srun[rt][r] += (idj != idr[rt][r]) ? e : 0.0f;                       \
        }                                                                      \
      }                                                                        \
    }                                                                          \
    __syncthreads();                                                           \
  }

  for (int t2 = 0; t2 < NCHUNK; t2 += 2) {
    FUSED_BODY(t2, 0)
    FUSED_BODY(t2 + 1, 1)
  }
#undef FUSED_BODY

  // sum across the 16 lanes of each quad (the 16 columns of the frag)
  #pragma unroll
  for (int rt = 0; rt < 2; ++rt)
    #pragma unroll
    for (int r = 0; r < 4; ++r) {
      float v = srun[rt][r];
      #pragma unroll
      for (int off = 1; off < 16; off <<= 1) v += __shfl_xor(v, off, 64);
      if (lpos == 0)
        atomicAdd(&ps[rowbase + rt * 16 + quad * 4 + r], v);
    }
}

// ---- finalize: per-row loss, mean ----
__global__ __launch_bounds__(256) void finalize_kernel(
    const float* __restrict__ ps, const float* __restrict__ pos,
    const float* __restrict__ q, const int* __restrict__ ids,
    const int* __restrict__ hist, float* __restrict__ out) {
  int i = blockIdx.x * 256 + threadIdx.x;   // 32 blocks -> 8192 threads
  const float s = ps[i];
  const float nm = (float)(MB - hist[ids[i]]);
  // log S_i = log(s) + C + log(1-q_i) - log(n_miss)
  const float z = logf(s) + COFF + logf(1.0f - q[i]) - logf(nm);
  const float p = pos[i];
  const float hi = fmaxf(p, z), lo = fminf(p, z);
  float loss = -p + hi + log1pf(__expf(lo - hi));

  #pragma unroll
  for (int off = 32; off; off >>= 1) loss += __shfl_down(loss, off, 64);
  __shared__ float red[4];
  if ((threadIdx.x & 63) == 0) red[threadIdx.x >> 6] = loss;
  __syncthreads();
  if (threadIdx.x == 0) {
    float t = red[0] + red[1] + red[2] + red[3];
    atomicAdd(out, t * (1.0f / (float)MB));
  }
}

extern "C" void kernel_launch(void* const* d_in, const int* in_sizes, int n_in,
                              void* d_out, int out_size, void* d_ws, size_t ws_size,
                              hipStream_t stream) {
  (void)in_sizes; (void)n_in; (void)out_size; (void)ws_size;
  const float* input_emb  = (const float*)d_in[0];
  const float* target_emb = (const float*)d_in[1];
  const int*   target_ids = (const int*)d_in[2];
  const float* q_probas   = (const float*)d_in[3];
  float* out = (float*)d_out;

  char* ws = (char*)d_ws;
  unsigned short* Abf = (unsigned short*)(ws);                    // 4 MB
  unsigned short* Bbf = (unsigned short*)(ws + (4u << 20));       // 4 MB
  int*   hist = (int*)  (ws + (8u << 20));                        // 4 MB
  float* b2   = (float*)(ws + (12u << 20));                       // 32 KB
  float* pos  = (float*)(ws + (12u << 20) + 32768);               // 32 KB
  float* ps   = (float*)(ws + (12u << 20) + 65536);               // 32 KB

  convertpos_kernel<<<2048, 256, 0, stream>>>(input_emb, target_emb, Abf, Bbf, pos, hist);
  histb2_kernel<<<32, 256, 0, stream>>>(target_ids, q_probas, hist, b2, ps, out);
  fused_kernel<<<dim3(MB / BM, NSPLIT), 256, 0, stream>>>(Abf, Bbf, target_ids, b2, ps);
  finalize_kernel<<<32, 256, 0, stream>>>(ps, pos, q_probas, target_ids, hist, out);
}